// Round 4
// baseline (60.707 us; speedup 1.0000x reference)
//
#include <hip/hip_runtime.h>
#include <hip/hip_bf16.h>

// Problem: B=N=1024, in_f=1024, OUT_F=32, KD=8
// out[n][0:1024]   = x[n][:]
// M[n][o*8+k]      = sum_f x[n][f] * T[f][o*8+k]        (T flat [1024][256])
// out[n][1024+o]   = sum_{i != n} exp(-sum_k |M[i][o*8+k] - M[n][o*8+k]|)

#define N_ROWS 1024
#define IN_F   1024
#define OUT_C  1056
#define OK     256   // OUT_F*KD
#define KS     16    // K-split factor
#define KC     64    // K-chunk = IN_F/KS
#define APITCH 132   // k-major A tile pitch (16B-aligned rows)

// ---------------- kernel 1: copy x into out + zero the o_b columns ----------
__global__ __launch_bounds__(256) void copy_x_kernel(
    const float* __restrict__ x, float* __restrict__ out) {
  int n = blockIdx.x;          // 0..1023
  int c = threadIdx.x * 4;     // 256 threads * 4 floats = 1024
  float4 v = *reinterpret_cast<const float4*>(x + (size_t)n * IN_F + c);
  *reinterpret_cast<float4*>(out + (size_t)n * OUT_C + c) = v;
  if (threadIdx.x < 8)         // zero-init out[n][1024:1056] for pairwise atomics
    *reinterpret_cast<float4*>(out + (size_t)n * OUT_C + 1024 + threadIdx.x * 4) =
        make_float4(0.f, 0.f, 0.f, 0.f);
}

// ---------------- kernel 2: fp32 GEMM, 128x128 tile, 8x8/thread, K-split 16 ----
__global__ __launch_bounds__(256) void gemm8_kernel(
    const float* __restrict__ A,   // x [1024][1024]
    const float* __restrict__ Bm,  // T [1024][256]
    float* __restrict__ part) {    // [KS][1024][256]
  __shared__ float as[KC][APITCH];   // k-major: as[k][row]
  __shared__ float bs[KC][128];      // row-major: bs[k][col]
  const int m0 = blockIdx.x * 128;
  const int n0 = blockIdx.y * 128;
  const int k0 = blockIdx.z * KC;
  const int t  = threadIdx.x;

#pragma unroll
  for (int u = 0; u < 8; ++u) {
    int idx = t + 256 * u;
    int row = idx >> 4, q4 = idx & 15;
    float4 v = *reinterpret_cast<const float4*>(A + (size_t)(m0 + row) * IN_F + k0 + q4 * 4);
    as[q4 * 4 + 0][row] = v.x;
    as[q4 * 4 + 1][row] = v.y;
    as[q4 * 4 + 2][row] = v.z;
    as[q4 * 4 + 3][row] = v.w;
  }
#pragma unroll
  for (int u = 0; u < 8; ++u) {
    int idx = t + 256 * u;
    int row = idx >> 5, c4 = idx & 31;
    *reinterpret_cast<float4*>(&bs[row][c4 * 4]) =
        *reinterpret_cast<const float4*>(Bm + (size_t)(k0 + row) * OK + n0 + c4 * 4);
  }
  __syncthreads();

  const int ty = t >> 4, tx = t & 15;
  float acc[8][8] = {};

#pragma unroll 4
  for (int kk = 0; kk < KC; ++kk) {
    float4 a0 = *reinterpret_cast<const float4*>(&as[kk][ty * 8]);
    float4 a1 = *reinterpret_cast<const float4*>(&as[kk][ty * 8 + 4]);
    float4 b0 = *reinterpret_cast<const float4*>(&bs[kk][tx * 4]);
    float4 b1 = *reinterpret_cast<const float4*>(&bs[kk][64 + tx * 4]);
    float ar[8] = {a0.x, a0.y, a0.z, a0.w, a1.x, a1.y, a1.z, a1.w};
    float br[8] = {b0.x, b0.y, b0.z, b0.w, b1.x, b1.y, b1.z, b1.w};
#pragma unroll
    for (int r = 0; r < 8; ++r)
#pragma unroll
      for (int c = 0; c < 8; ++c)
        acc[r][c] = fmaf(ar[r], br[c], acc[r][c]);
  }

  float* dst = part + (size_t)blockIdx.z * (N_ROWS * OK);
#pragma unroll
  for (int r = 0; r < 8; ++r) {
    int row = m0 + ty * 8 + r;
    *reinterpret_cast<float4*>(&dst[(size_t)row * OK + n0 + tx * 4]) =
        make_float4(acc[r][0], acc[r][1], acc[r][2], acc[r][3]);
    *reinterpret_cast<float4*>(&dst[(size_t)row * OK + n0 + 64 + tx * 4]) =
        make_float4(acc[r][4], acc[r][5], acc[r][6], acc[r][7]);
  }
}

// ---------------- kernel 2b: reduce K-split partials ----------------
__global__ __launch_bounds__(256) void reduce_kernel(
    const float* __restrict__ part, float* __restrict__ M) {
  int g = blockIdx.x * 256 + threadIdx.x;
  const float4* p = reinterpret_cast<const float4*>(part);
  float4 s = p[g];
#pragma unroll
  for (int sl = 1; sl < KS; ++sl) {
    float4 v = p[g + (size_t)sl * (N_ROWS * OK / 4)];
    s.x += v.x; s.y += v.y; s.z += v.z; s.w += v.w;
  }
  reinterpret_cast<float4*>(M)[g] = s;
}

// ---------------- fallback GEMM (small ws): single-pass ----------------
#define BK 16
__global__ __launch_bounds__(256) void gemm32_kernel(
    const float* __restrict__ A, const float* __restrict__ Bm, float* __restrict__ M) {
  __shared__ float as2[BK][32];
  __shared__ float bs2[BK][32];
  int m0 = blockIdx.x * 32;
  int n0 = blockIdx.y * 32;
  int t  = threadIdx.x;
  int ty = t >> 4, tx = t & 15;
  float c00 = 0.f, c01 = 0.f, c10 = 0.f, c11 = 0.f;
  for (int k0 = 0; k0 < IN_F; k0 += BK) {
    if (t < 128) {
      int row = t >> 2, q = t & 3;
      float4 v = *reinterpret_cast<const float4*>(A + (size_t)(m0 + row) * IN_F + k0 + q * 4);
      as2[q * 4 + 0][row] = v.x; as2[q * 4 + 1][row] = v.y;
      as2[q * 4 + 2][row] = v.z; as2[q * 4 + 3][row] = v.w;
    } else {
      int tt = t - 128;
      int row = tt >> 3, q = tt & 7;
      float4 v = *reinterpret_cast<const float4*>(Bm + (size_t)(k0 + row) * OK + n0 + q * 4);
      *reinterpret_cast<float4*>(&bs2[row][q * 4]) = v;
    }
    __syncthreads();
#pragma unroll
    for (int kk = 0; kk < BK; ++kk) {
      float2 a = *reinterpret_cast<const float2*>(&as2[kk][ty * 2]);
      float2 b = *reinterpret_cast<const float2*>(&bs2[kk][tx * 2]);
      c00 += a.x * b.x; c01 += a.x * b.y;
      c10 += a.y * b.x; c11 += a.y * b.y;
    }
    __syncthreads();
  }
  int r = m0 + ty * 2, c = n0 + tx * 2;
  M[(size_t)r * OK + c]           = c00;
  M[(size_t)r * OK + c + 1]       = c01;
  M[(size_t)(r + 1) * OK + c]     = c10;
  M[(size_t)(r + 1) * OK + c + 1] = c11;
}

// ---------------- kernel 3: pairwise exp(-L1), LDS i-rows, 4 j/thread --------
// grid (o:32, jt:4, is:2) = 256 blocks, 512 threads (8 waves).
// Each thread holds 4 j-rows (j = jt*256 + q*64 + jl) in registers; wave s
// iterates i in [is*512 + s*64, +64) reading staged LDS rows (broadcast,
// conflict-free). Per-block partials -> LDS reduce -> one atomicAdd per (j,o).
__global__ __launch_bounds__(512) void pairwise4_kernel(
    const float* __restrict__ M, float* __restrict__ out) {
  __shared__ float sm[512][8];      // 16 KB: this block's i-rows
  __shared__ float red[8][64][5];   // padded (+1) partial sums

  const int o  = blockIdx.x;   // 0..31
  const int jt = blockIdx.y;   // 0..3
  const int is = blockIdx.z;   // 0..1
  const int t  = threadIdx.x;
  const int jl = t & 63, s = t >> 6;

  const float* Mo = M + o * 8;

  // stage 512 i-rows (is half): 1024 float4, coalesced, conflict-free
  for (int idx = t; idx < 1024; idx += 512) {
    int row = idx >> 1, half = idx & 1;
    *reinterpret_cast<float4*>(&sm[row][half * 4]) =
        *reinterpret_cast<const float4*>(Mo + (size_t)(is * 512 + row) * OK + half * 4);
  }

  // 4 j-rows into registers (hidden behind the staging barrier)
  float rj[4][8];
#pragma unroll
  for (int q = 0; q < 4; ++q) {
    int j = jt * 256 + q * 64 + jl;
    *reinterpret_cast<float4*>(&rj[q][0]) =
        *reinterpret_cast<const float4*>(Mo + (size_t)j * OK);
    *reinterpret_cast<float4*>(&rj[q][4]) =
        *reinterpret_cast<const float4*>(Mo + (size_t)j * OK + 4);
  }
  __syncthreads();

  float acc[4] = {0.f, 0.f, 0.f, 0.f};
  const int ib = s * 64;
#pragma unroll 4
  for (int ii = 0; ii < 64; ++ii) {
    float4 va = *reinterpret_cast<const float4*>(&sm[ib + ii][0]);
    float4 vb = *reinterpret_cast<const float4*>(&sm[ib + ii][4]);
#pragma unroll
    for (int q = 0; q < 4; ++q) {
      float d = (fabsf(va.x - rj[q][0]) + fabsf(va.y - rj[q][1])) +
                (fabsf(va.z - rj[q][2]) + fabsf(va.w - rj[q][3])) +
                (fabsf(vb.x - rj[q][4]) + fabsf(vb.y - rj[q][5])) +
                (fabsf(vb.z - rj[q][6]) + fabsf(vb.w - rj[q][7]));
      // exp(-d) < e^-30: total contribution < 1e-10 over 1024 terms -> skip
      if (d < 30.f) acc[q] += __expf(-d);
    }
  }

  // remove exact self term: j's i-block (j>>6 = jt*4+q) vs this wave's block
#pragma unroll
  for (int q = 0; q < 4; ++q)
    if (jt * 4 + q == is * 8 + s) acc[q] -= 1.f;

  red[s][jl][0] = acc[0]; red[s][jl][1] = acc[1];
  red[s][jl][2] = acc[2]; red[s][jl][3] = acc[3];
  __syncthreads();

  if (t < 256) {
    int q = t >> 6, l = t & 63;
    float v = 0.f;
#pragma unroll
    for (int w = 0; w < 8; ++w) v += red[w][l][q];
    int j = jt * 256 + q * 64 + l;
    atomicAdd(&out[(size_t)j * OUT_C + 1024 + o], v);
  }
}

extern "C" void kernel_launch(void* const* d_in, const int* in_sizes, int n_in,
                              void* d_out, int out_size, void* d_ws, size_t ws_size,
                              hipStream_t stream) {
  const float* x = (const float*)d_in[0];   // [1024][1024]
  const float* T = (const float*)d_in[1];   // [1024][256]
  float* out = (float*)d_out;               // [1024][1056]

  copy_x_kernel<<<dim3(N_ROWS), dim3(256), 0, stream>>>(x, out);

  const size_t mBytes    = (size_t)N_ROWS * OK * sizeof(float);   // 1 MB
  const size_t partBytes = (size_t)KS * mBytes;                   // 16 MB

  if (ws_size >= partBytes + mBytes) {
    float* part = (float*)d_ws;
    float* M    = (float*)((char*)d_ws + partBytes);
    gemm8_kernel<<<dim3(8, 2, KS), dim3(256), 0, stream>>>(x, T, part);
    reduce_kernel<<<dim3(256), dim3(256), 0, stream>>>(part, M);
    pairwise4_kernel<<<dim3(32, 4, 2), dim3(512), 0, stream>>>(M, out);
  } else {
    float* M = (float*)d_ws;
    gemm32_kernel<<<dim3(32, 8), dim3(256), 0, stream>>>(x, T, M);
    pairwise4_kernel<<<dim3(32, 4, 2), dim3(512), 0, stream>>>(M, out);
  }
}

// Round 5
// 51.382 us; speedup vs baseline: 1.1815x; 1.1815x over previous
//
#include <hip/hip_runtime.h>
#include <hip/hip_bf16.h>

// Problem: B=N=1024, in_f=1024, OUT_F=32, KD=8
// out[n][0:1024]   = x[n][:]
// M[n][o*8+k]      = sum_f x[n][f] * T[f][o*8+k]        (T flat [1024][256])
// out[n][1024+o]   = sum_{i != n} exp(-sum_k |M[i][o*8+k] - M[n][o*8+k]|)

#define N_ROWS 1024
#define IN_F   1024
#define OUT_C  1056
#define OK     256   // OUT_F*KD
#define KS     8     // K-split factor
#define KC     128   // K-chunk = IN_F/KS

// ---------------- kernel 1: copy x into out + zero the o_b columns ----------
__global__ __launch_bounds__(256) void copy_x_kernel(
    const float* __restrict__ x, float* __restrict__ out) {
  int n = blockIdx.x;          // 0..1023
  int c = threadIdx.x * 4;     // 256 threads * 4 floats = 1024
  float4 v = *reinterpret_cast<const float4*>(x + (size_t)n * IN_F + c);
  *reinterpret_cast<float4*>(out + (size_t)n * OUT_C + c) = v;
  if (threadIdx.x < 8)         // zero-init out[n][1024:1056] for pairwise atomics
    *reinterpret_cast<float4*>(out + (size_t)n * OUT_C + 1024 + threadIdx.x * 4) =
        make_float4(0.f, 0.f, 0.f, 0.f);
}

// ---------------- kernel 2: fp32 GEMM with K-split (R1-proven) ----------------
// part[ks][1024][256]; block (bm,bn,ks) computes 64x64 tile over K-chunk 128.
// One-shot LDS staging, ONE barrier, then pure compute (4x4 per thread).
__global__ __launch_bounds__(256) void gemm_split_kernel(
    const float* __restrict__ A,   // x [1024][1024]
    const float* __restrict__ Bm,  // T [1024][256]
    float* __restrict__ part) {    // [KS][1024][256]
  __shared__ float as[64][KC + 4];   // row-major A tile, +4 pad
  __shared__ float bs[KC][64];
  const int m0 = blockIdx.x * 64;
  const int n0 = blockIdx.y * 64;
  const int ks = blockIdx.z;
  const int k0 = ks * KC;
  const int t  = threadIdx.x;

  // stage A: 64 rows x 128 k = 2048 float4, 8 per thread, coalesced
#pragma unroll
  for (int u = 0; u < 8; ++u) {
    int f = t + 256 * u;
    int row = f >> 5, fk = f & 31;           // KC/4 = 32 float4 per row
    float4 v = *reinterpret_cast<const float4*>(A + (size_t)(m0 + row) * IN_F + k0 + fk * 4);
    *reinterpret_cast<float4*>(&as[row][fk * 4]) = v;
  }
  // stage B: 128 k x 64 cols = 2048 float4
#pragma unroll
  for (int u = 0; u < 8; ++u) {
    int f = t + 256 * u;
    int row = f >> 4, fc = f & 15;
    float4 v = *reinterpret_cast<const float4*>(Bm + (size_t)(k0 + row) * OK + n0 + fc * 4);
    *reinterpret_cast<float4*>(&bs[row][fc * 4]) = v;
  }
  __syncthreads();

  const int ty = t >> 4, tx = t & 15;   // 16x16 thread grid, 4x4 outputs each
  float acc[4][4] = {};

  for (int kk = 0; kk < KC; kk += 4) {
    float av[4][4], bv[4][4];
#pragma unroll
    for (int r = 0; r < 4; ++r)
      *reinterpret_cast<float4*>(av[r]) = *reinterpret_cast<const float4*>(&as[ty * 4 + r][kk]);
#pragma unroll
    for (int i = 0; i < 4; ++i)
      *reinterpret_cast<float4*>(bv[i]) = *reinterpret_cast<const float4*>(&bs[kk + i][tx * 4]);
#pragma unroll
    for (int i = 0; i < 4; ++i)
#pragma unroll
      for (int r = 0; r < 4; ++r)
#pragma unroll
        for (int c = 0; c < 4; ++c)
          acc[r][c] = fmaf(av[r][i], bv[i][c], acc[r][c]);
  }

  float* dst = part + (size_t)ks * N_ROWS * OK;
#pragma unroll
  for (int r = 0; r < 4; ++r)
    *reinterpret_cast<float4*>(&dst[(size_t)(m0 + ty * 4 + r) * OK + n0 + tx * 4]) =
        *reinterpret_cast<const float4*>(acc[r]);
}

// ---------------- kernel 2b: reduce K-split partials ----------------
__global__ __launch_bounds__(256) void reduce_kernel(
    const float* __restrict__ part, float* __restrict__ M) {
  int g = blockIdx.x * 256 + threadIdx.x;         // 65536 float4 groups
  const float4* p = reinterpret_cast<const float4*>(part);
  float4 s = p[g];
#pragma unroll
  for (int sl = 1; sl < KS; ++sl) {
    float4 v = p[g + (size_t)sl * (N_ROWS * OK / 4)];
    s.x += v.x; s.y += v.y; s.z += v.z; s.w += v.w;
  }
  reinterpret_cast<float4*>(M)[g] = s;
}

// ---------------- fallback GEMM (small ws): single-pass ----------------
#define BK 16
__global__ __launch_bounds__(256) void gemm32_kernel(
    const float* __restrict__ A, const float* __restrict__ Bm, float* __restrict__ M) {
  __shared__ float as2[BK][32];
  __shared__ float bs2[BK][32];
  int m0 = blockIdx.x * 32;
  int n0 = blockIdx.y * 32;
  int t  = threadIdx.x;
  int ty = t >> 4, tx = t & 15;
  float c00 = 0.f, c01 = 0.f, c10 = 0.f, c11 = 0.f;
  for (int k0 = 0; k0 < IN_F; k0 += BK) {
    if (t < 128) {
      int row = t >> 2, q = t & 3;
      float4 v = *reinterpret_cast<const float4*>(A + (size_t)(m0 + row) * IN_F + k0 + q * 4);
      as2[q * 4 + 0][row] = v.x; as2[q * 4 + 1][row] = v.y;
      as2[q * 4 + 2][row] = v.z; as2[q * 4 + 3][row] = v.w;
    } else {
      int tt = t - 128;
      int row = tt >> 3, q = tt & 7;
      float4 v = *reinterpret_cast<const float4*>(Bm + (size_t)(k0 + row) * OK + n0 + q * 4);
      *reinterpret_cast<float4*>(&bs2[row][q * 4]) = v;
    }
    __syncthreads();
#pragma unroll
    for (int kk = 0; kk < BK; ++kk) {
      float2 a = *reinterpret_cast<const float2*>(&as2[kk][ty * 2]);
      float2 b = *reinterpret_cast<const float2*>(&bs2[kk][tx * 2]);
      c00 += a.x * b.x; c01 += a.x * b.y;
      c10 += a.y * b.x; c11 += a.y * b.y;
    }
    __syncthreads();
  }
  int r = m0 + ty * 2, c = n0 + tx * 2;
  M[(size_t)r * OK + c]           = c00;
  M[(size_t)r * OK + c + 1]       = c01;
  M[(size_t)(r + 1) * OK + c]     = c10;
  M[(size_t)(r + 1) * OK + c + 1] = c11;
}

// ---------------- kernel 3: pairwise exp(-L1) v5 -----------------------------
// grid (o:32, jt:4, is:2) = 256 blocks, 512 threads (8 waves).
// Each thread owns 4 j-rows in NAMED float4 registers (no arrays -> no scratch);
// wave s iterates i in [is*512 + s*64, +64) from staged LDS (broadcast reads).
// Per-block partials -> padded-LDS reduce -> one atomicAdd per (j,o) (2 contenders).
__global__ __launch_bounds__(512) void pairwise5_kernel(
    const float* __restrict__ M, float* __restrict__ out) {
  __shared__ float sm[512][8];      // 16 KB: this block's i-rows
  __shared__ float red[8][64][5];   // padded (+1) partial sums

  const int o  = blockIdx.x;   // 0..31
  const int jt = blockIdx.y;   // 0..3
  const int is = blockIdx.z;   // 0..1
  const int t  = threadIdx.x;
  const int jl = t & 63, s = t >> 6;
  const int isw = is * 8 + s;  // this wave's global i-block (0..15)

  const float* Mo = M + o * 8;

  // stage 512 i-rows (is half): 1024 float4, coalesced, conflict-free
  for (int idx = t; idx < 1024; idx += 512) {
    int row = idx >> 1, half = idx & 1;
    *reinterpret_cast<float4*>(&sm[row][half * 4]) =
        *reinterpret_cast<const float4*>(Mo + (size_t)(is * 512 + row) * OK + half * 4);
  }

  // 4 j-rows into NAMED registers (hidden behind staging barrier)
  const int jb = jt * 256 + jl;
  float4 ra0 = *reinterpret_cast<const float4*>(Mo + (size_t)(jb)       * OK);
  float4 rb0 = *reinterpret_cast<const float4*>(Mo + (size_t)(jb)       * OK + 4);
  float4 ra1 = *reinterpret_cast<const float4*>(Mo + (size_t)(jb + 64)  * OK);
  float4 rb1 = *reinterpret_cast<const float4*>(Mo + (size_t)(jb + 64)  * OK + 4);
  float4 ra2 = *reinterpret_cast<const float4*>(Mo + (size_t)(jb + 128) * OK);
  float4 rb2 = *reinterpret_cast<const float4*>(Mo + (size_t)(jb + 128) * OK + 4);
  float4 ra3 = *reinterpret_cast<const float4*>(Mo + (size_t)(jb + 192) * OK);
  float4 rb3 = *reinterpret_cast<const float4*>(Mo + (size_t)(jb + 192) * OK + 4);
  __syncthreads();

  float acc0 = 0.f, acc1 = 0.f, acc2 = 0.f, acc3 = 0.f;
  const int ib = s * 64;
  for (int ii = 0; ii < 64; ++ii) {
    float4 va = *reinterpret_cast<const float4*>(&sm[ib + ii][0]);
    float4 vb = *reinterpret_cast<const float4*>(&sm[ib + ii][4]);
    float d0 = (fabsf(va.x - ra0.x) + fabsf(va.y - ra0.y)) +
               (fabsf(va.z - ra0.z) + fabsf(va.w - ra0.w)) +
               (fabsf(vb.x - rb0.x) + fabsf(vb.y - rb0.y)) +
               (fabsf(vb.z - rb0.z) + fabsf(vb.w - rb0.w));
    float d1 = (fabsf(va.x - ra1.x) + fabsf(va.y - ra1.y)) +
               (fabsf(va.z - ra1.z) + fabsf(va.w - ra1.w)) +
               (fabsf(vb.x - rb1.x) + fabsf(vb.y - rb1.y)) +
               (fabsf(vb.z - rb1.z) + fabsf(vb.w - rb1.w));
    float d2 = (fabsf(va.x - ra2.x) + fabsf(va.y - ra2.y)) +
               (fabsf(va.z - ra2.z) + fabsf(va.w - ra2.w)) +
               (fabsf(vb.x - rb2.x) + fabsf(vb.y - rb2.y)) +
               (fabsf(vb.z - rb2.z) + fabsf(vb.w - rb2.w));
    float d3 = (fabsf(va.x - ra3.x) + fabsf(va.y - ra3.y)) +
               (fabsf(va.z - ra3.z) + fabsf(va.w - ra3.w)) +
               (fabsf(vb.x - rb3.x) + fabsf(vb.y - rb3.y)) +
               (fabsf(vb.z - rb3.z) + fabsf(vb.w - rb3.w));
    // One guard for all 4 pairs. Body almost never executes (min d over the
    // dataset ~23; guard at 30 keeps omitted mass < 1e-10 over 1024 terms).
    // Inside, exp(-d) for large d underflows to 0 harmlessly.
    float dmin = fminf(fminf(d0, d1), fminf(d2, d3));
    if (dmin < 30.f) {
      acc0 += __expf(-d0);
      acc1 += __expf(-d1);
      acc2 += __expf(-d2);
      acc3 += __expf(-d3);
    }
  }

  // remove exact self term: j's i-block (jt*4+q) vs this wave's block isw
  if (jt * 4 + 0 == isw) acc0 -= 1.f;
  if (jt * 4 + 1 == isw) acc1 -= 1.f;
  if (jt * 4 + 2 == isw) acc2 -= 1.f;
  if (jt * 4 + 3 == isw) acc3 -= 1.f;

  red[s][jl][0] = acc0; red[s][jl][1] = acc1;
  red[s][jl][2] = acc2; red[s][jl][3] = acc3;
  __syncthreads();

  if (t < 256) {
    int q = t >> 6, l = t & 63;
    float v = 0.f;
#pragma unroll
    for (int w = 0; w < 8; ++w) v += red[w][l][q];
    int j = jt * 256 + q * 64 + l;
    atomicAdd(&out[(size_t)j * OUT_C + 1024 + o], v);
  }
}

extern "C" void kernel_launch(void* const* d_in, const int* in_sizes, int n_in,
                              void* d_out, int out_size, void* d_ws, size_t ws_size,
                              hipStream_t stream) {
  const float* x = (const float*)d_in[0];   // [1024][1024]
  const float* T = (const float*)d_in[1];   // [1024][256]
  float* out = (float*)d_out;               // [1024][1056]

  copy_x_kernel<<<dim3(N_ROWS), dim3(256), 0, stream>>>(x, out);

  const size_t mBytes    = (size_t)N_ROWS * OK * sizeof(float);   // 1 MB
  const size_t partBytes = (size_t)KS * mBytes;                   // 8 MB

  if (ws_size >= partBytes + mBytes) {
    float* part = (float*)d_ws;
    float* M    = (float*)((char*)d_ws + partBytes);
    gemm_split_kernel<<<dim3(16, 4, KS), dim3(256), 0, stream>>>(x, T, part);
    reduce_kernel<<<dim3(256), dim3(256), 0, stream>>>(part, M);
    pairwise5_kernel<<<dim3(32, 4, 2), dim3(512), 0, stream>>>(M, out);
  } else {
    float* M = (float*)d_ws;
    gemm32_kernel<<<dim3(32, 8), dim3(256), 0, stream>>>(x, T, M);
    pairwise5_kernel<<<dim3(32, 4, 2), dim3(512), 0, stream>>>(M, out);
  }
}

// Round 6
// 42.262 us; speedup vs baseline: 1.4365x; 1.2158x over previous
//
#include <hip/hip_runtime.h>
#include <hip/hip_bf16.h>

// Problem: B=N=1024, in_f=1024, OUT_F=32, KD=8
// out[n][0:1024]   = x[n][:]
// M[n][o*8+k]      = sum_f x[n][f] * T[f][o*8+k]        (T flat [1024][256])
// out[n][1024+o]   = sum_{i != n} exp(-sum_k |M[i][o*8+k] - M[n][o*8+k]|)
//
// 3 graph nodes: gemm_split -> reduce_copy -> pairwise. (R1-proven components;
// R5 change is ONLY node consolidation: 5 launches -> 3.)

#define N_ROWS 1024
#define IN_F   1024
#define OUT_C  1056
#define OK     256   // OUT_F*KD
#define KS     8     // K-split factor
#define KC     128   // K-chunk = IN_F/KS

// ---------------- kernel 1: fp32 GEMM with K-split (R1-proven, verbatim) -----
// part[ks][1024][256]; block (bm,bn,ks) computes 64x64 tile over K-chunk 128.
// One-shot LDS staging, ONE barrier, then pure compute (4x4 per thread).
__global__ __launch_bounds__(256) void gemm_split_kernel(
    const float* __restrict__ A,   // x [1024][1024]
    const float* __restrict__ Bm,  // T [1024][256]
    float* __restrict__ part) {    // [KS][1024][256]
  __shared__ float as[64][KC + 4];   // row-major A tile, +4 pad
  __shared__ float bs[KC][64];
  const int m0 = blockIdx.x * 64;
  const int n0 = blockIdx.y * 64;
  const int ks = blockIdx.z;
  const int k0 = ks * KC;
  const int t  = threadIdx.x;

  // stage A: 64 rows x 128 k = 2048 float4, 8 per thread, coalesced
#pragma unroll
  for (int u = 0; u < 8; ++u) {
    int f = t + 256 * u;
    int row = f >> 5, fk = f & 31;           // KC/4 = 32 float4 per row
    float4 v = *reinterpret_cast<const float4*>(A + (size_t)(m0 + row) * IN_F + k0 + fk * 4);
    *reinterpret_cast<float4*>(&as[row][fk * 4]) = v;
  }
  // stage B: 128 k x 64 cols = 2048 float4
#pragma unroll
  for (int u = 0; u < 8; ++u) {
    int f = t + 256 * u;
    int row = f >> 4, fc = f & 15;
    float4 v = *reinterpret_cast<const float4*>(Bm + (size_t)(k0 + row) * OK + n0 + fc * 4);
    *reinterpret_cast<float4*>(&bs[row][fc * 4]) = v;
  }
  __syncthreads();

  const int ty = t >> 4, tx = t & 15;   // 16x16 thread grid, 4x4 outputs each
  float acc[4][4] = {};

  for (int kk = 0; kk < KC; kk += 4) {
    float av[4][4], bv[4][4];
#pragma unroll
    for (int r = 0; r < 4; ++r)
      *reinterpret_cast<float4*>(av[r]) = *reinterpret_cast<const float4*>(&as[ty * 4 + r][kk]);
#pragma unroll
    for (int i = 0; i < 4; ++i)
      *reinterpret_cast<float4*>(bv[i]) = *reinterpret_cast<const float4*>(&bs[kk + i][tx * 4]);
#pragma unroll
    for (int i = 0; i < 4; ++i)
#pragma unroll
      for (int r = 0; r < 4; ++r)
#pragma unroll
        for (int c = 0; c < 4; ++c)
          acc[r][c] = fmaf(av[r][i], bv[i][c], acc[r][c]);
  }

  float* dst = part + (size_t)ks * N_ROWS * OK;
#pragma unroll
  for (int r = 0; r < 4; ++r)
    *reinterpret_cast<float4*>(&dst[(size_t)(m0 + ty * 4 + r) * OK + n0 + tx * 4]) =
        *reinterpret_cast<const float4*>(acc[r]);
}

// ---------------- kernel 2: reduce K-split partials + copy x into out --------
// grid 512 x 256 threads. Waves 0-1 (t<128) also reduce; all threads copy.
__global__ __launch_bounds__(256) void reduce_copy_kernel(
    const float* __restrict__ part, float* __restrict__ M,
    const float* __restrict__ x, float* __restrict__ out) {
  const int b = blockIdx.x, t = threadIdx.x;

  // reduce: 65536 float4 groups total, 128 per block
  if (t < 128) {
    int g = b * 128 + t;
    const float4* p = reinterpret_cast<const float4*>(part);
    float4 s = p[g];
#pragma unroll
    for (int sl = 1; sl < KS; ++sl) {
      float4 v = p[g + (size_t)sl * (N_ROWS * OK / 4)];
      s.x += v.x; s.y += v.y; s.z += v.z; s.w += v.w;
    }
    reinterpret_cast<float4*>(M)[g] = s;
  }

  // copy x -> out[:, 0:1024]: 262144 float4 total, 512 per block
#pragma unroll
  for (int u = 0; u < 2; ++u) {
    int idx = b * 512 + u * 256 + t;
    int row = idx >> 8, col4 = idx & 255;     // 256 float4 per row
    float4 v = *reinterpret_cast<const float4*>(x + (size_t)row * IN_F + col4 * 4);
    *reinterpret_cast<float4*>(out + (size_t)row * OUT_C + col4 * 4) = v;
  }
}

// ---------------- fallback GEMM (small ws): single-pass ----------------
#define BK 16
__global__ __launch_bounds__(256) void gemm32_kernel(
    const float* __restrict__ A, const float* __restrict__ Bm, float* __restrict__ M) {
  __shared__ float as2[BK][32];
  __shared__ float bs2[BK][32];
  int m0 = blockIdx.x * 32;
  int n0 = blockIdx.y * 32;
  int t  = threadIdx.x;
  int ty = t >> 4, tx = t & 15;
  float c00 = 0.f, c01 = 0.f, c10 = 0.f, c11 = 0.f;
  for (int k0 = 0; k0 < IN_F; k0 += BK) {
    if (t < 128) {
      int row = t >> 2, q = t & 3;
      float4 v = *reinterpret_cast<const float4*>(A + (size_t)(m0 + row) * IN_F + k0 + q * 4);
      as2[q * 4 + 0][row] = v.x; as2[q * 4 + 1][row] = v.y;
      as2[q * 4 + 2][row] = v.z; as2[q * 4 + 3][row] = v.w;
    } else {
      int tt = t - 128;
      int row = tt >> 3, q = tt & 7;
      float4 v = *reinterpret_cast<const float4*>(Bm + (size_t)(k0 + row) * OK + n0 + q * 4);
      *reinterpret_cast<float4*>(&bs2[row][q * 4]) = v;
    }
    __syncthreads();
#pragma unroll
    for (int kk = 0; kk < BK; ++kk) {
      float2 a = *reinterpret_cast<const float2*>(&as2[kk][ty * 2]);
      float2 b = *reinterpret_cast<const float2*>(&bs2[kk][tx * 2]);
      c00 += a.x * b.x; c01 += a.x * b.y;
      c10 += a.y * b.x; c11 += a.y * b.y;
    }
    __syncthreads();
  }
  int r = m0 + ty * 2, c = n0 + tx * 2;
  M[(size_t)r * OK + c]           = c00;
  M[(size_t)r * OK + c + 1]       = c01;
  M[(size_t)(r + 1) * OK + c]     = c10;
  M[(size_t)(r + 1) * OK + c + 1] = c11;
}

// ---------------- kernel 3: pairwise exp(-L1) (R1-proven, verbatim) ----------
// grid = (o: 32, jt: 16) = 512 blocks, 256 threads, stages all 1024 i-rows.
__global__ __launch_bounds__(256) void pairwise_kernel(
    const float* __restrict__ M, float* __restrict__ out) {
  __shared__ float sm[N_ROWS][8];   // 32 KB: M[:, o, :]
  __shared__ float red[4][64];

  int o  = blockIdx.x;
  int jt = blockIdx.y;
  int t  = threadIdx.x;

#pragma unroll
  for (int idx = t; idx < 2048; idx += 256) {
    int row = idx >> 1, half = idx & 1;
    *reinterpret_cast<float4*>(&sm[row][half * 4]) =
        *reinterpret_cast<const float4*>(M + (size_t)row * OK + o * 8 + half * 4);
  }
  __syncthreads();

  int jl = t & 63, s = t >> 6;
  int j  = jt * 64 + jl;

  float4 ra = *reinterpret_cast<const float4*>(&sm[j][0]);
  float4 rb = *reinterpret_cast<const float4*>(&sm[j][4]);

  float acc = 0.f;
  int i0 = s * 256;
  for (int i = i0; i < i0 + 256; ++i) {
    float4 va = *reinterpret_cast<const float4*>(&sm[i][0]);
    float4 vb = *reinterpret_cast<const float4*>(&sm[i][4]);
    float d = fabsf(va.x - ra.x) + fabsf(va.y - ra.y) +
              fabsf(va.z - ra.z) + fabsf(va.w - ra.w) +
              fabsf(vb.x - rb.x) + fabsf(vb.y - rb.y) +
              fabsf(vb.z - rb.z) + fabsf(vb.w - rb.w);
    // exp(-d) < e^-30: contributes < 1e-10 total over 1024 terms -> skip
    if (d < 30.f) acc += __expf(-d);
  }
  if ((j >> 8) == s) acc -= 1.0f;   // exact self term exp(0)=1

  red[s][jl] = acc;
  __syncthreads();

  if (t < 64) {
    float v = red[0][t] + red[1][t] + red[2][t] + red[3][t];
    int jj = jt * 64 + t;
    out[(size_t)jj * OUT_C + 1024 + o] = v;
  }
}

// fallback copy (only used on fallback path)
__global__ __launch_bounds__(256) void copy_x_kernel(
    const float* __restrict__ x, float* __restrict__ out) {
  int n = blockIdx.x;
  int c = threadIdx.x * 4;
  float4 v = *reinterpret_cast<const float4*>(x + (size_t)n * IN_F + c);
  *reinterpret_cast<float4*>(out + (size_t)n * OUT_C + c) = v;
}

extern "C" void kernel_launch(void* const* d_in, const int* in_sizes, int n_in,
                              void* d_out, int out_size, void* d_ws, size_t ws_size,
                              hipStream_t stream) {
  const float* x = (const float*)d_in[0];   // [1024][1024]
  const float* T = (const float*)d_in[1];   // [1024][256]
  float* out = (float*)d_out;               // [1024][1056]

  const size_t mBytes    = (size_t)N_ROWS * OK * sizeof(float);   // 1 MB
  const size_t partBytes = (size_t)KS * mBytes;                   // 8 MB

  if (ws_size >= partBytes + mBytes) {
    float* part = (float*)d_ws;
    float* M    = (float*)((char*)d_ws + partBytes);
    gemm_split_kernel<<<dim3(16, 4, KS), dim3(256), 0, stream>>>(x, T, part);
    reduce_copy_kernel<<<dim3(512), dim3(256), 0, stream>>>(part, M, x, out);
    pairwise_kernel<<<dim3(32, 16), dim3(256), 0, stream>>>(M, out);
  } else {
    float* M = (float*)d_ws;
    copy_x_kernel<<<dim3(N_ROWS), dim3(256), 0, stream>>>(x, out);
    gemm32_kernel<<<dim3(32, 8), dim3(256), 0, stream>>>(x, T, M);
    pairwise_kernel<<<dim3(32, 16), dim3(256), 0, stream>>>(M, out);
  }
}